// Round 14
// baseline (98.586 us; speedup 1.0000x reference)
//
#include <hip/hip_runtime.h>
#include <hip/hip_fp16.h>
#include <stdint.h>

typedef unsigned int  u32;
typedef unsigned short u16;

#define B_ROWS 131072
#define P_PRED 64
#define C_CLS  128
#define NPAIR  384               // C*L raw words for dtype detection
#define CAP    32                // max records per predicate (mean 6)
#define RPB    128               // rows per block (2 rows per thread)
#define TPB    512               // 8 waves; wave g owns predicates [8g, 8g+8)
#define GCAP   104               // record capacity per 8-pred group (mean 48)
#define LOG2E  1.4426950408889634f

#if __has_builtin(__builtin_amdgcn_exp2f)
#define EXP2F(x) __builtin_amdgcn_exp2f(x)
#else
#define EXP2F(x) exp2f(x)
#endif

#if __has_builtin(__builtin_amdgcn_rcpf)
#define RCPF(x) __builtin_amdgcn_rcpf(x)
#else
#define RCPF(x) (1.0f / (x))
#endif

__device__ __forceinline__ float bf16_to_f(u16 u) {
    return __uint_as_float(((u32)u) << 16);
}
__device__ __forceinline__ u16 f_to_bf16(float f) {
    u32 u = __float_as_uint(f);
    u += 0x7FFFu + ((u >> 16) & 1u);   // RNE
    return (u16)(u >> 16);
}
__device__ __forceinline__ u32 pack_bf16x2(float lo, float hi) {
    return (u32)f_to_bf16(lo) | ((u32)f_to_bf16(hi) << 16);
}
// fp16 pair helpers (u32 <-> __half2 bitcasts)
__device__ __forceinline__ u32 h2u(__half2 h) { union { __half2 h; u32 u; } v; v.h = h; return v.u; }
__device__ __forceinline__ __half2 u2h(u32 u) { union { __half2 h; u32 u; } v; v.u = u; return v.h; }
__device__ __forceinline__ u32 pack_f16x2(float lo, float hi) {
    return h2u(__floats2half2_rn(lo, hi));     // RN: 2x v_cvt_f16_f32 + pack
}

// ---------------------------------------------------------------------------
// R24 = R23 (97.06us best: R-table + b128 record pairs) + SELF-CAPTURE FROM
// STAGING. Instruction audit: phase 1b had grown to ~80 DS instr/wave (48 E2
// reads + 16 R writes + 16 self preload reads) — MORE than the record loop's
// ~72. The 16 self-preload reads are redundant: wave g stages exactly atoms
// 8g..8g+8 (slots 16g..16g+16), and lane a stages its own rows (2a, 2a+1) —
// precisely the words S[slot][lane] the preload re-reads. This round captures
// the packed half2 values in REGISTERS during staging (both dtype branches)
// and deletes the preload. Bit-identical values; -16 DS instr/thread (~9% of
// all DS traffic) and the associated lgkm waits. Everything else unchanged
// from passing R23.
// Workspace d_ws: UNUSED.
// ---------------------------------------------------------------------------
__global__ __launch_bounds__(TPB, 8)
void ke_selfcap(const u32* __restrict__ lidx_w,
                const u32* __restrict__ sb_w,
                const u32* __restrict__ w_w,
                const void* __restrict__ atoms_v,
                void* __restrict__ out_v) {
    __shared__ u32 S[8192];                          // 32 KB: scratch -> E2 -> R
    __shared__ __align__(16) uint2 srec[8 * GCAP];   // 6656 B (persists)
    __shared__ unsigned char cnt8[P_PRED];           // 64 B stored counts
    __shared__ u32 cslotS[C_CLS];                    // 512 B clause slot triples

    const int tid = threadIdx.x;
    const int lane = tid & 63;
    const int g = __builtin_amdgcn_readfirstlane(tid >> 6);  // 0..7, SGPR
    const int rowBase = blockIdx.x * RPB;

    // ======== phase 0: inline prep (scratch aliased into S) ========
    int*   scnt  = (int*)&S[0];       // [64]
    int*   det   = (int*)&S[64];      // [3]
    int*   sidx  = (int*)&S[128];     // [384]
    int*   ssb   = (int*)&S[512];     // [384]
    u32*   recPk = &S[1024];          // [64][32]
    u32*   recWH = &S[3072];          // [64][32] pre-signed half2-dup weight

    if (tid < P_PRED) scnt[tid] = 0;
    if (tid < 3) det[tid] = 1;
    // zero srec so inter-stream pad slots are harmless (w=+0 records)
    srec[tid] = make_uint2(0u, 0u);
    if (tid < 8 * GCAP - TPB) srec[TPB + tid] = make_uint2(0u, 0u);
    __syncthreads();
    if (tid < NPAIR / 2) {
        if (lidx_w[2 * tid + 1] != 0u) det[0] = 0;   // benign race (all write 0)
        if (sb_w[2 * tid + 1]   != 0u) det[1] = 0;
    }
    if (tid == 0 && (w_w[0] & 0xFFFFu) == 0u) det[2] = 0;
    __syncthreads();
    if (tid < NPAIR) {
        sidx[tid] = (int)(det[0] ? lidx_w[2 * tid] : lidx_w[tid]);
        ssb[tid]  = (int)(det[1] ? sb_w[2 * tid]   : sb_w[tid]);
    }
    __syncthreads();
    const bool bf16m = (det[2] != 0);            // latch before S is reused
    if (tid < NPAIR) {
        const int c = tid / 3;
        const int p = sidx[tid];
        const int slot = atomicAdd(&scnt[p], 1); // prep-only LDS atomics: fine
        float wraw = bf16m ? bf16_to_f((u16)(w_w[c / 2] >> ((c & 1) * 16)))
                           : __uint_as_float(w_w[c]);
        float wc = fminf(fmaxf(wraw, 0.0f), 500.0f);
        if (slot < CAP) {
            recPk[p * CAP + slot] = (u32)c << 8;          // R-table byte offset
            u32 wh2 = pack_f16x2(wc, wc);                 // duplicated half2
            if (!ssb[tid]) wh2 ^= 0x80008000u;            // pre-signed (sign bit
            recWH[p * CAP + slot] = wh2;                  //  also keys self-select)
        }
    }
    if (tid < C_CLS) {
        const int c = tid;
        const u32 s0 = 2u * (u32)sidx[3 * c]     + (ssb[3 * c]     ? 0u : 1u);
        const u32 s1 = 2u * (u32)sidx[3 * c + 1] + (ssb[3 * c + 1] ? 0u : 1u);
        const u32 s2 = 2u * (u32)sidx[3 * c + 2] + (ssb[3 * c + 2] ? 0u : 1u);
        cslotS[c] = s0 | (s1 << 8) | (s2 << 16);
    }
    __syncthreads();
    // CSR copy with EVEN-ALIGNED stream starts (pads stay zero)
    if (tid < P_PRED) {
        const int p = tid;
        const int gg = p >> 3;
        const int n = min(scnt[p], CAP);
        int off = 0;
        for (int pb = gg * 8; pb < p; ++pb)
            off += (min(scnt[pb], CAP) + 1) & ~1;        // padded counts
        int ncl = 0;
        for (int j = 0; j < n; ++j) {
            if (off + j < GCAP) {
                srec[gg * GCAP + off + j] =
                    make_uint2(recPk[p * CAP + j], recWH[p * CAP + j]);
                ++ncl;
            }
        }
        if ((ncl & 1) && off + ncl >= GCAP) --ncl;       // keep pad slot in-group
        cnt8[p] = (unsigned char)ncl;
    }
    __syncthreads();   // srec/cnt8 ready; prep scratch in S now dead

    // ======== phase 1: stage E2 as half2 + SELF-CAPTURE in registers ======
    // Wave g stages atoms 8g..8g+8 (slots 16g..16g+16); lane a stages its own
    // rows (2a, 2a+1) — so the packed values ARE this lane's selfP/selfN.
    u32 selfP[8], selfN[8];
    {
        const int a = tid & 63;                  // row pair (2a, 2a+1)
        const int c0 = (tid >> 6) * 8;           // 8-atom chunk
        if (bf16m) {
            const u16* gp0 = (const u16*)atoms_v + (size_t)(rowBase + 2 * a) * P_PRED + c0;
            uint4 v0 = *(const uint4*)gp0;            // row 2a
            uint4 v1 = *(const uint4*)(gp0 + P_PRED); // row 2a+1
            u32 w0[4] = {v0.x, v0.y, v0.z, v0.w};
            u32 w1[4] = {v1.x, v1.y, v1.z, v1.w};
#pragma unroll
            for (int k = 0; k < 4; ++k) {
                float xl0 = __uint_as_float(w0[k] << 16) * LOG2E;
                float xh0 = __uint_as_float(w0[k] & 0xFFFF0000u) * LOG2E;
                float xl1 = __uint_as_float(w1[k] << 16) * LOG2E;
                float xh1 = __uint_as_float(w1[k] & 0xFFFF0000u) * LOG2E;
                float el0 = EXP2F(xl0), eh0 = EXP2F(xh0);
                float el1 = EXP2F(xl1), eh1 = EXP2F(xh1);
                const int m = c0 + 2 * k;
                const u32 pe  = pack_f16x2(el0, el1);
                const u32 pr  = pack_f16x2(RCPF(el0), RCPF(el1));
                const u32 qe  = pack_f16x2(eh0, eh1);
                const u32 qr  = pack_f16x2(RCPF(eh0), RCPF(eh1));
                S[(2 * m)     * 64 + a] = pe;
                S[(2 * m + 1) * 64 + a] = pr;
                S[(2 * m + 2) * 64 + a] = qe;
                S[(2 * m + 3) * 64 + a] = qr;
                selfP[2 * k]     = pe;  selfN[2 * k]     = pr;
                selfP[2 * k + 1] = qe;  selfN[2 * k + 1] = qr;
            }
        } else {
            const float* gp0 = (const float*)atoms_v + (size_t)(rowBase + 2 * a) * P_PRED + c0;
            float4 u0 = *(const float4*)gp0;
            float4 u1 = *(const float4*)(gp0 + 4);
            float4 d0 = *(const float4*)(gp0 + P_PRED);
            float4 d1 = *(const float4*)(gp0 + P_PRED + 4);
            float r0[8] = {u0.x, u0.y, u0.z, u0.w, u1.x, u1.y, u1.z, u1.w};
            float r1[8] = {d0.x, d0.y, d0.z, d0.w, d1.x, d1.y, d1.z, d1.w};
#pragma unroll
            for (int k = 0; k < 8; ++k) {
                float e0 = EXP2F(r0[k] * LOG2E);
                float e1 = EXP2F(r1[k] * LOG2E);
                const int m = c0 + k;
                const u32 pe = pack_f16x2(e0, e1);
                const u32 pr = pack_f16x2(RCPF(e0), RCPF(e1));
                S[(2 * m)     * 64 + a] = pe;
                S[(2 * m + 1) * 64 + a] = pr;
                selfP[k] = pe;  selfN[k] = pr;
            }
        }
    }
    __syncthreads();

    // ======== phase 1b: in-place R table (self already in registers) ======
    u32 rt[16];
#pragma unroll
    for (int k = 0; k < 16; ++k) {
        const int c  = g * 16 + k;                 // wave-uniform clause
        const u32 cs = cslotS[c];                  // broadcast LDS read
        const u32 e0 = S[((cs      ) & 255u) * 64 + lane];
        const u32 e1 = S[((cs >>  8) & 255u) * 64 + lane];
        const u32 e2 = S[((cs >> 16) & 255u) * 64 + lane];
        const __half2 D = __hadd2(u2h(e0), __hadd2(u2h(e1), u2h(e2)));
        rt[k] = h2u(h2rcp(D));
    }
    __syncthreads();       // ALL E2 reads complete (incl. other waves')
#pragma unroll
    for (int k = 0; k < 16; ++k) S[(g * 16 + k) * 64 + lane] = rt[k];
    __syncthreads();       // R table ready

    // ======== phase 2: record loop (b128 pairs, 1 fma post-load) ========
    const int q2 = 2 * lane;                     // u16 row index of this row pair
    const char* Rc = (const char*)S + lane * 4;  // per-lane R base (byte)
    float2 acc[8];
    int j = g * GCAP;                            // stream cursor (even starts)

#pragma unroll
    for (int pp = 0; pp < 8; ++pp) {
        const int n = (int)cnt8[pp + g * 8];
        const int npair = (n + 1) >> 1;          // pad slot is zero -> harmless
        const u32 sp = selfP[pp], sn = selfN[pp];
        __half2 a0 = u2h(0u), a1 = u2h(0u);
        __half2 a2 = u2h(0u), a3 = u2h(0u);

#define PAIR_BODY(J, A, B)                                                    \
        {                                                                     \
            const uint4 q = *(const uint4*)&srec[J];   /* 2 records, b128 */  \
            const u32 R0 = *(const u32*)(Rc + (q.x & 0x7F00u));               \
            const u32 R1 = *(const u32*)(Rc + (q.z & 0x7F00u));               \
            const u32 s0 = ((int)q.y < 0) ? sn : sp;                          \
            const u32 s1 = ((int)q.w < 0) ? sn : sp;                          \
            const __half2 m0 = __hmul2(u2h(s0), u2h(q.y));  /* pre-R-load */  \
            const __half2 m1 = __hmul2(u2h(s1), u2h(q.w));                    \
            A = __hfma2(u2h(R0), m0, A);               /* 1 fma post-load */  \
            B = __hfma2(u2h(R1), m1, B);                                      \
        }

        int k = 0;
        for (; k + 1 < npair; k += 2, j += 4) {  // 2 pairs (4 records) / iter
            PAIR_BODY(j,     a0, a1)
            PAIR_BODY(j + 2, a2, a3)
        }
        for (; k < npair; ++k, j += 2) PAIR_BODY(j, a0, a1)
#undef PAIR_BODY
        // j has advanced 2*npair = (n+1)&~1 slots — the padded count.

        const __half2 at = __hadd2(__hadd2(a0, a1), __hadd2(a2, a3));
        acc[pp] = make_float2(__low2float(at), __high2float(at));
    }

    // ======== phase 3: direct stores (R9 epilogue) ========
    if (bf16m) {
        u16* op0 = (u16*)out_v + (size_t)(rowBase + q2) * P_PRED + g * 8;
        u16* op1 = op0 + P_PRED;
        uint4 o0, o1v;
        o0.x  = pack_bf16x2(acc[0].x, acc[1].x);
        o0.y  = pack_bf16x2(acc[2].x, acc[3].x);
        o0.z  = pack_bf16x2(acc[4].x, acc[5].x);
        o0.w  = pack_bf16x2(acc[6].x, acc[7].x);
        o1v.x = pack_bf16x2(acc[0].y, acc[1].y);
        o1v.y = pack_bf16x2(acc[2].y, acc[3].y);
        o1v.z = pack_bf16x2(acc[4].y, acc[5].y);
        o1v.w = pack_bf16x2(acc[6].y, acc[7].y);
        *(uint4*)op0 = o0;
        *(uint4*)op1 = o1v;
    } else {
        float* op0 = (float*)out_v + (size_t)(rowBase + q2) * P_PRED + g * 8;
        float* op1 = op0 + P_PRED;
        *(float4*)(op0)     = make_float4(acc[0].x, acc[1].x, acc[2].x, acc[3].x);
        *(float4*)(op0 + 4) = make_float4(acc[4].x, acc[5].x, acc[6].x, acc[7].x);
        *(float4*)(op1)     = make_float4(acc[0].y, acc[1].y, acc[2].y, acc[3].y);
        *(float4*)(op1 + 4) = make_float4(acc[4].y, acc[5].y, acc[6].y, acc[7].y);
    }
}

extern "C" void kernel_launch(void* const* d_in, const int* in_sizes, int n_in,
                              void* d_out, int out_size, void* d_ws, size_t ws_size,
                              hipStream_t stream_h) {
    const u32* clause_weights = (const u32*)d_in[1]; // bf16 or f32 [128]
    const u32* literal_idx    = (const u32*)d_in[2]; // int32 or int64 [128,3]
    const u32* sign_bits      = (const u32*)d_in[3]; // int32 or int64 [128,3]
    (void)d_ws; (void)ws_size;                       // workspace unused

    ke_selfcap<<<B_ROWS / RPB, TPB, 0, stream_h>>>(literal_idx, sign_bits,
                                                   clause_weights, d_in[0],
                                                   d_out);
}